// Round 5
// baseline (1664.308 us; speedup 1.0000x reference)
//
#include <hip/hip_runtime.h>

#define T_DIM 2048
#define B_DIM 50
#define F_DIM 750
#define H_DIM 100
#define G4    400             // 4*H
#define M_DIM (T_DIM * B_DIM) // 102400
#define KPAD  768             // F padded to MFMA-friendly K

typedef __attribute__((ext_vector_type(8))) short short8v;  // 8 bf16
typedef __attribute__((ext_vector_type(4))) float f32x4;
typedef __attribute__((ext_vector_type(2))) float f32x2;

__device__ __forceinline__ float fast_rcp(float x) { return __builtin_amdgcn_rcpf(x); }
__device__ __forceinline__ float tanh_f(float x) {
    return 1.0f - 2.0f * fast_rcp(__expf(2.0f * x) + 1.0f);
}

__device__ __forceinline__ unsigned short f2bf_rne(float f) {
    unsigned int u = __float_as_uint(f);
    u = (u + 0x7FFFu + ((u >> 16) & 1u)) >> 16;
    return (unsigned short)u;
}
__device__ __forceinline__ float bf2f(unsigned short h) {
    return __uint_as_float(((unsigned int)h) << 16);
}

template <int CTRL>
__device__ __forceinline__ float qperm(float x) {
    return __int_as_float(__builtin_amdgcn_mov_dpp(__float_as_int(x), CTRL, 0xF, 0xF, false));
}

// ---------------------------------------------------------------------------
// Kernel 0: W_ih (400x750 fp32) -> W_hi/W_lo (400x768 bf16, k-padded 0). RNE.
// ---------------------------------------------------------------------------
__global__ __launch_bounds__(256) void wconv(
    const float* __restrict__ W,
    unsigned short* __restrict__ Whi,
    unsigned short* __restrict__ Wlo)
{
    int i = blockIdx.x * 256 + threadIdx.x;
    if (i >= G4 * KPAD) return;
    int g = i / KPAD, k = i - g * KPAD;
    float v = (k < F_DIM) ? W[g * F_DIM + k] : 0.f;
    unsigned short h = f2bf_rne(v);
    Whi[i] = h;
    Wlo[i] = f2bf_rne(v - bf2f(h));
}

// ---------------------------------------------------------------------------
// Kernel 1: xp = x @ W_ih^T + b via bf16 split MFMA.  M-tile 128, 8 waves.
//   Wave w: row-block (w>>2)*64, col-set w&3 (7 of 25 16-col tiles).
//   T14 async-stage: global loads issued BEFORE MFMA cluster, convert+ds_write
//   after. Truncation hi/lo split (residual MFMA absorbs the error).
// ---------------------------------------------------------------------------
__global__ __launch_bounds__(512, 1) void xproj_mfma(
    const float* __restrict__ x,            // (M, 750)
    const unsigned short* __restrict__ Whi, // (400, 768) bf16
    const unsigned short* __restrict__ Wlo,
    const float* __restrict__ bih,
    const float* __restrict__ bhh,
    float* __restrict__ xp)                 // (M, 400)
{
    const int m0   = blockIdx.x * 128;
    const int tid  = threadIdx.x;
    const int lane = tid & 63;
    const int w    = tid >> 6;            // wave 0..7
    const int rb   = (w >> 2) * 64;       // row block 0 / 64
    const int wc   = w & 3;               // col wave 0..3
    const int fr   = lane & 15;
    const int fk   = (lane >> 4) * 8;

    __shared__ unsigned short Ahi[2][128][40];   // 20 KB
    __shared__ unsigned short Alo[2][128][40];   // 20 KB

    f32x4 acc[4][7];
    #pragma unroll
    for (int s = 0; s < 4; ++s)
        #pragma unroll
        for (int t = 0; t < 7; ++t)
            acc[s][t] = (f32x4){0.f, 0.f, 0.f, 0.f};

    float bias_t[7];
    #pragma unroll
    for (int tt = 0; tt < 7; ++tt) {
        const int nt = wc + 4 * tt;
        if (nt < 25) {
            const int n = nt * 16 + fr;
            bias_t[tt] = bih[n] + bhh[n];
        } else bias_t[tt] = 0.f;
    }

    const int sr = tid >> 2;          // row 0..127
    const int sc = (tid & 3) * 8;     // k-chunk 0/8/16/24
    const float* xrow = x + (size_t)(m0 + sr) * F_DIM;

    float f[8];

    #define STAGE_LOAD(KS)                                                     \
    {                                                                          \
        const int kg = (KS) * 32 + sc;                                         \
        _Pragma("unroll")                                                      \
        for (int i = 0; i < 8; i += 2) {                                       \
            if (kg + i + 1 < F_DIM) {                                          \
                float2 v = *reinterpret_cast<const float2*>(&xrow[kg + i]);    \
                f[i] = v.x; f[i + 1] = v.y;                                    \
            } else {                                                           \
                f[i]     = (kg + i < F_DIM) ? xrow[kg + i] : 0.f;              \
                f[i + 1] = 0.f;                                                \
            }                                                                  \
        }                                                                      \
    }

    #define STAGE_WRITE(NB)                                                    \
    {                                                                          \
        short8v vh, vl;                                                        \
        _Pragma("unroll")                                                      \
        for (int i = 0; i < 8; ++i) {                                          \
            unsigned int u = __float_as_uint(f[i]);                            \
            vh[i] = (short)(u >> 16);                                          \
            float r = f[i] - __uint_as_float(u & 0xffff0000u);                 \
            vl[i] = (short)(__float_as_uint(r) >> 16);                         \
        }                                                                      \
        *reinterpret_cast<short8v*>(&Ahi[NB][sr][sc]) = vh;                    \
        *reinterpret_cast<short8v*>(&Alo[NB][sr][sc]) = vl;                    \
    }

    STAGE_LOAD(0);
    STAGE_WRITE(0);
    asm volatile("s_waitcnt lgkmcnt(0)\ns_barrier" ::: "memory");

    for (int s = 0; s < 24; ++s) {
        const int cur = s & 1;
        short8v ah[4], al[4];
        #pragma unroll
        for (int st = 0; st < 4; ++st) {
            ah[st] = *reinterpret_cast<const short8v*>(&Ahi[cur][rb + st * 16 + fr][fk]);
            al[st] = *reinterpret_cast<const short8v*>(&Alo[cur][rb + st * 16 + fr][fk]);
        }

        if (s < 23) STAGE_LOAD(s + 1);    // issue loads early; consume after MFMA

        const int kb = s * 32 + fk;
        #pragma unroll
        for (int tt = 0; tt < 7; ++tt) {
            const int nt = wc + 4 * tt;
            if (nt < 25) {
                const int n = nt * 16 + fr;
                const short8v bh = *reinterpret_cast<const short8v*>(&Whi[n * KPAD + kb]);
                const short8v bl = *reinterpret_cast<const short8v*>(&Wlo[n * KPAD + kb]);
                #pragma unroll
                for (int st = 0; st < 4; ++st) {
                    acc[st][tt] = __builtin_amdgcn_mfma_f32_16x16x32_bf16(ah[st], bh, acc[st][tt], 0, 0, 0);
                    acc[st][tt] = __builtin_amdgcn_mfma_f32_16x16x32_bf16(ah[st], bl, acc[st][tt], 0, 0, 0);
                    acc[st][tt] = __builtin_amdgcn_mfma_f32_16x16x32_bf16(al[st], bh, acc[st][tt], 0, 0, 0);
                }
            }
        }

        if (s < 23) STAGE_WRITE(cur ^ 1); // vmcnt wait lands here, after MFMAs
        asm volatile("s_waitcnt lgkmcnt(0)\ns_barrier" ::: "memory");
    }

    // C/D layout: col = lane&15, row = (lane>>4)*4 + reg  [m89-verified]
    #pragma unroll
    for (int tt = 0; tt < 7; ++tt) {
        const int nt = wc + 4 * tt;
        if (nt < 25) {
            const int n = nt * 16 + fr;
            #pragma unroll
            for (int st = 0; st < 4; ++st) {
                #pragma unroll
                for (int r = 0; r < 4; ++r) {
                    const int m = m0 + rb + st * 16 + (lane >> 4) * 4 + r;
                    xp[(size_t)m * G4 + n] = acc[st][tt][r] + bias_t[tt];
                }
            }
        }
    }
    #undef STAGE_LOAD
    #undef STAGE_WRITE
}

// ---------------------------------------------------------------------------
// Kernel 2: LSTM scan, quarter-split quad cell.
//   Weights as f32x2 pairs -> v_pk_fma_f32 (56 pk_fma/lane/step), PINNED in
//   VGPRs via empty asm redefinition (defeats loop remat - the round-4 bug).
//   xp prefetched 2 steps ahead. One lgkm-only barrier per step.
// ---------------------------------------------------------------------------
__global__ __launch_bounds__(448, 1) void lstm_scan(
    const float* __restrict__ xp,    // (T*B, 400)
    const float* __restrict__ Whh,   // (400, 100)
    float* __restrict__ hs)          // (T*B, 100)
{
    const int b   = blockIdx.x;
    const int tid = threadIdx.x;
    const int q   = tid & 3;         // k-quarter / gate lane
    const int j   = tid >> 2;        // hidden unit 0..111
    const int jc  = (j < H_DIM) ? j : (H_DIM - 1);
    const int row = q * H_DIM + jc;  // xp column for gate q of unit j

    __shared__ __align__(16) float hbuf[2][112];   // quarters at 28-float offsets

    // w2[g][r] = (Whh[g*100+jc][25q+2r], [25q+2r+1]); r<14, pads zero.
    f32x2 w2[4][14];
    #pragma unroll
    for (int g = 0; g < 4; ++g) {
        const float* base = Whh + (size_t)(g * H_DIM + jc) * H_DIM + 25 * q;
        #pragma unroll
        for (int r = 0; r < 12; ++r)
            w2[g][r] = (f32x2){base[2 * r], base[2 * r + 1]};
        w2[g][12] = (f32x2){base[24], 0.f};
        w2[g][13] = (f32x2){0.f, 0.f};
    }
    // PIN: opaque redefinition -> compiler cannot re-load from Whh inside loop
    #pragma unroll
    for (int g = 0; g < 4; ++g)
        #pragma unroll
        for (int r = 0; r < 14; ++r)
            asm volatile("" : "+v"(w2[g][r]));

    if (tid < 112) { hbuf[0][tid] = 0.f; hbuf[1][tid] = 0.f; }

    const int hpos = (jc / 25) * 28 + (jc % 25);
    const bool writer = (q == 0) && (j < H_DIM);

    // unified activation: act = s*sigm(s*x) - (s-1); s=2 for tanh gate (q==2)
    const float s_act = (q == 2) ? 2.0f : 1.0f;
    const float nsl2  = -s_act * 1.44269504088896f;
    const float nsm1  = 1.0f - s_act;

    float c = 0.f;
    const float* xp_ptr = xp + (size_t)b * G4 + row;
    float*       hs_ptr = hs + (size_t)b * H_DIM + j;
    const size_t xstride = (size_t)B_DIM * G4;

    float xpv   = xp_ptr[0];
    float xp_n1 = xp_ptr[xstride];
    __syncthreads();

    int p = 0;
    for (int t = 0; t < T_DIM; ++t) {
        float xp_n2 = 0.f;
        if (t + 2 < T_DIM) xp_n2 = xp_ptr[2 * xstride];   // uniform branch
        xp_ptr += xstride;

        // packed partial dots over this lane's 28-float (padded) quarter
        f32x2 a0 = {0.f, 0.f}, a1 = {0.f, 0.f}, a2 = {0.f, 0.f}, a3 = {0.f, 0.f};
        const float* hq = &hbuf[p][28 * q];
        #pragma unroll
        for (int k4 = 0; k4 < 7; ++k4) {
            float4 hv = *reinterpret_cast<const float4*>(hq + 4 * k4);
            f32x2 hlo = {hv.x, hv.y};
            f32x2 hhi = {hv.z, hv.w};
            a0 = __builtin_elementwise_fma(w2[0][2 * k4],     hlo, a0);
            a0 = __builtin_elementwise_fma(w2[0][2 * k4 + 1], hhi, a0);
            a1 = __builtin_elementwise_fma(w2[1][2 * k4],     hlo, a1);
            a1 = __builtin_elementwise_fma(w2[1][2 * k4 + 1], hhi, a1);
            a2 = __builtin_elementwise_fma(w2[2][2 * k4],     hlo, a2);
            a2 = __builtin_elementwise_fma(w2[2][2 * k4 + 1], hhi, a2);
            a3 = __builtin_elementwise_fma(w2[3][2 * k4],     hlo, a3);
            a3 = __builtin_elementwise_fma(w2[3][2 * k4 + 1], hhi, a3);
        }
        float ac0 = a0.x + a0.y + ((q == 0) ? xpv : 0.f);
        float ac1 = a1.x + a1.y + ((q == 1) ? xpv : 0.f);
        float ac2 = a2.x + a2.y + ((q == 2) ? xpv : 0.f);
        float ac3 = a3.x + a3.y + ((q == 3) ? xpv : 0.f);

        // quad butterfly (VALU DPP): full sums in all lanes
        ac0 += qperm<0xB1>(ac0);
        ac1 += qperm<0xB1>(ac1);
        ac2 += qperm<0xB1>(ac2);
        ac3 += qperm<0xB1>(ac3);
        ac0 += qperm<0x4E>(ac0);
        ac1 += qperm<0x4E>(ac1);
        ac2 += qperm<0x4E>(ac2);
        ac3 += qperm<0x4E>(ac3);

        // lane q activates only gate q
        float pre = ac0;
        pre = (q == 1) ? ac1 : pre;
        pre = (q == 2) ? ac2 : pre;
        pre = (q == 3) ? ac3 : pre;
        float act = fmaf(s_act, fast_rcp(1.0f + __builtin_amdgcn_exp2f(nsl2 * pre)), nsm1);

        // broadcast i,f,g,o across the quad
        float i_ = qperm<0x00>(act);
        float f_ = qperm<0x55>(act);
        float g_ = qperm<0xAA>(act);
        float o_ = qperm<0xFF>(act);

        c = fmaf(f_, c, i_ * g_);
        const float h = o_ * tanh_f(c);

        if (writer) {
            hbuf[p ^ 1][hpos] = h;
            *hs_ptr = h;
        }
        hs_ptr += B_DIM * H_DIM;
        asm volatile("s_waitcnt lgkmcnt(0)\ns_barrier" ::: "memory");
        p ^= 1;
        xpv   = xp_n1;
        xp_n1 = xp_n2;
    }
}

// ---------------------------------------------------------------------------
// Kernel 3: FC. out[t,o] = fc_b[o] + hs[t,:] . fcW[o,:]
// ---------------------------------------------------------------------------
__global__ __launch_bounds__(256) void fc_kernel(
    const float* __restrict__ hs,    // (T, 5000)
    const float* __restrict__ fcW,   // (2, 5000)
    const float* __restrict__ fcb,
    float* __restrict__ out)         // (T, 2)
{
    const int t   = blockIdx.x;
    const int tid = threadIdx.x;

    float p0 = 0.f, p1 = 0.f;
    for (int k = tid * 4; k < 5000; k += 1024) {
        const float4 hv = *reinterpret_cast<const float4*>(&hs[(size_t)t * 5000 + k]);
        const float4 w0 = *reinterpret_cast<const float4*>(&fcW[k]);
        const float4 w1 = *reinterpret_cast<const float4*>(&fcW[5000 + k]);
        p0 += hv.x * w0.x + hv.y * w0.y + hv.z * w0.z + hv.w * w0.w;
        p1 += hv.x * w1.x + hv.y * w1.y + hv.z * w1.z + hv.w * w1.w;
    }
    #pragma unroll
    for (int off = 32; off > 0; off >>= 1) {
        p0 += __shfl_xor(p0, off);
        p1 += __shfl_xor(p1, off);
    }
    __shared__ float red[8];
    const int wv = tid >> 6;
    if ((tid & 63) == 0) { red[wv * 2] = p0; red[wv * 2 + 1] = p1; }
    __syncthreads();
    if (tid == 0) {
        out[2 * t]     = fcb[0] + red[0] + red[2] + red[4] + red[6];
        out[2 * t + 1] = fcb[1] + red[1] + red[3] + red[5] + red[7];
    }
}

// ---------------------------------------------------------------------------
extern "C" void kernel_launch(void* const* d_in, const int* in_sizes, int n_in,
                              void* d_out, int out_size, void* d_ws, size_t ws_size,
                              hipStream_t stream) {
    const float* x   = (const float*)d_in[0];
    const float* Wih = (const float*)d_in[1];
    const float* Whh = (const float*)d_in[2];
    const float* bih = (const float*)d_in[3];
    const float* bhh = (const float*)d_in[4];
    const float* fcW = (const float*)d_in[5];
    const float* fcb = (const float*)d_in[6];
    float* out = (float*)d_out;

    // ws layout: xp (163.84 MB) | Whi (614.4 KB) | Wlo (614.4 KB) | hs (40.96 MB)
    char* ws = (char*)d_ws;
    float*          xp  = (float*)ws;
    unsigned short* Whi = (unsigned short*)(ws + (size_t)M_DIM * G4 * 4);
    unsigned short* Wlo = Whi + (size_t)G4 * KPAD;
    float*          hs  = (float*)((char*)(Wlo + (size_t)G4 * KPAD));

    wconv<<<(G4 * KPAD + 255) / 256, 256, 0, stream>>>(Wih, Whi, Wlo);

    xproj_mfma<<<M_DIM / 128, 512, 0, stream>>>(x, Whi, Wlo, bih, bhh, xp);

    lstm_scan<<<B_DIM, 448, 0, stream>>>(xp, Whh, hs);

    fc_kernel<<<T_DIM, 256, 0, stream>>>(hs, fcW, fcb, out);
}

// Round 7
// 1646.369 us; speedup vs baseline: 1.0109x; 1.0109x over previous
//
#include <hip/hip_runtime.h>

#define T_DIM 2048
#define B_DIM 50
#define F_DIM 750
#define H_DIM 100
#define G4    400             // 4*H
#define M_DIM (T_DIM * B_DIM) // 102400
#define KPAD  768             // F padded to MFMA-friendly K

typedef __attribute__((ext_vector_type(8))) short short8v;  // 8 bf16
typedef __attribute__((ext_vector_type(4))) float f32x4;
typedef __attribute__((ext_vector_type(2))) float f32x2;

__device__ __forceinline__ float fast_rcp(float x) { return __builtin_amdgcn_rcpf(x); }
__device__ __forceinline__ float tanh_f(float x) {
    return 1.0f - 2.0f * fast_rcp(__expf(2.0f * x) + 1.0f);
}

__device__ __forceinline__ unsigned short f2bf_rne(float f) {
    unsigned int u = __float_as_uint(f);
    u = (u + 0x7FFFu + ((u >> 16) & 1u)) >> 16;
    return (unsigned short)u;
}
__device__ __forceinline__ float bf2f(unsigned short h) {
    return __uint_as_float(((unsigned int)h) << 16);
}

template <int CTRL>
__device__ __forceinline__ float qperm(float x) {
    return __int_as_float(__builtin_amdgcn_mov_dpp(__float_as_int(x), CTRL, 0xF, 0xF, false));
}

// lgkm-only barrier, fenced against scheduler motion (rule #18 hygiene)
__device__ __forceinline__ void lgkm_barrier() {
    __builtin_amdgcn_sched_barrier(0);
    asm volatile("s_waitcnt lgkmcnt(0)\ns_barrier" ::: "memory");
    __builtin_amdgcn_sched_barrier(0);
}

// ---------------------------------------------------------------------------
// Kernel 0: W_ih (400x750 fp32) -> W_hi/W_lo (400x768 bf16, k-padded 0). RNE.
// ---------------------------------------------------------------------------
__global__ __launch_bounds__(256) void wconv(
    const float* __restrict__ W,
    unsigned short* __restrict__ Whi,
    unsigned short* __restrict__ Wlo)
{
    int i = blockIdx.x * 256 + threadIdx.x;
    if (i >= G4 * KPAD) return;
    int g = i / KPAD, k = i - g * KPAD;
    float v = (k < F_DIM) ? W[g * F_DIM + k] : 0.f;
    unsigned short h = f2bf_rne(v);
    Whi[i] = h;
    Wlo[i] = f2bf_rne(v - bf2f(h));
}

// ---------------------------------------------------------------------------
// Kernel 1: xp = x @ W_ih^T + b via bf16 split MFMA.  M-tile 128, 8 waves.
// ---------------------------------------------------------------------------
__global__ __launch_bounds__(512, 1) void xproj_mfma(
    const float* __restrict__ x,            // (M, 750)
    const unsigned short* __restrict__ Whi, // (400, 768) bf16
    const unsigned short* __restrict__ Wlo,
    const float* __restrict__ bih,
    const float* __restrict__ bhh,
    float* __restrict__ xp)                 // (M, 400)
{
    const int m0   = blockIdx.x * 128;
    const int tid  = threadIdx.x;
    const int lane = tid & 63;
    const int w    = tid >> 6;            // wave 0..7
    const int rb   = (w >> 2) * 64;       // row block 0 / 64
    const int wc   = w & 3;               // col wave 0..3
    const int fr   = lane & 15;
    const int fk   = (lane >> 4) * 8;

    __shared__ unsigned short Ahi[2][128][40];   // 20 KB
    __shared__ unsigned short Alo[2][128][40];   // 20 KB

    f32x4 acc[4][7];
    #pragma unroll
    for (int s = 0; s < 4; ++s)
        #pragma unroll
        for (int t = 0; t < 7; ++t)
            acc[s][t] = (f32x4){0.f, 0.f, 0.f, 0.f};

    float bias_t[7];
    #pragma unroll
    for (int tt = 0; tt < 7; ++tt) {
        const int nt = wc + 4 * tt;
        if (nt < 25) {
            const int n = nt * 16 + fr;
            bias_t[tt] = bih[n] + bhh[n];
        } else bias_t[tt] = 0.f;
    }

    const int sr = tid >> 2;          // row 0..127
    const int sc = (tid & 3) * 8;     // k-chunk 0/8/16/24
    const float* xrow = x + (size_t)(m0 + sr) * F_DIM;

    float f[8];

    #define STAGE_LOAD(KS)                                                     \
    {                                                                          \
        const int kg = (KS) * 32 + sc;                                         \
        _Pragma("unroll")                                                      \
        for (int i = 0; i < 8; i += 2) {                                       \
            if (kg + i + 1 < F_DIM) {                                          \
                float2 v = *reinterpret_cast<const float2*>(&xrow[kg + i]);    \
                f[i] = v.x; f[i + 1] = v.y;                                    \
            } else {                                                           \
                f[i]     = (kg + i < F_DIM) ? xrow[kg + i] : 0.f;              \
                f[i + 1] = 0.f;                                                \
            }                                                                  \
        }                                                                      \
    }

    #define STAGE_WRITE(NB)                                                    \
    {                                                                          \
        short8v vh, vl;                                                        \
        _Pragma("unroll")                                                      \
        for (int i = 0; i < 8; ++i) {                                          \
            unsigned int u = __float_as_uint(f[i]);                            \
            vh[i] = (short)(u >> 16);                                          \
            float r = f[i] - __uint_as_float(u & 0xffff0000u);                 \
            vl[i] = (short)(__float_as_uint(r) >> 16);                         \
        }                                                                      \
        *reinterpret_cast<short8v*>(&Ahi[NB][sr][sc]) = vh;                    \
        *reinterpret_cast<short8v*>(&Alo[NB][sr][sc]) = vl;                    \
    }

    STAGE_LOAD(0);
    STAGE_WRITE(0);
    lgkm_barrier();

    for (int s = 0; s < 24; ++s) {
        const int cur = s & 1;
        short8v ah[4], al[4];
        #pragma unroll
        for (int st = 0; st < 4; ++st) {
            ah[st] = *reinterpret_cast<const short8v*>(&Ahi[cur][rb + st * 16 + fr][fk]);
            al[st] = *reinterpret_cast<const short8v*>(&Alo[cur][rb + st * 16 + fr][fk]);
        }

        if (s < 23) STAGE_LOAD(s + 1);    // issue loads early; consume after MFMA

        const int kb = s * 32 + fk;
        #pragma unroll
        for (int tt = 0; tt < 7; ++tt) {
            const int nt = wc + 4 * tt;
            if (nt < 25) {
                const int n = nt * 16 + fr;
                const short8v bh = *reinterpret_cast<const short8v*>(&Whi[n * KPAD + kb]);
                const short8v bl = *reinterpret_cast<const short8v*>(&Wlo[n * KPAD + kb]);
                #pragma unroll
                for (int st = 0; st < 4; ++st) {
                    acc[st][tt] = __builtin_amdgcn_mfma_f32_16x16x32_bf16(ah[st], bh, acc[st][tt], 0, 0, 0);
                    acc[st][tt] = __builtin_amdgcn_mfma_f32_16x16x32_bf16(ah[st], bl, acc[st][tt], 0, 0, 0);
                    acc[st][tt] = __builtin_amdgcn_mfma_f32_16x16x32_bf16(al[st], bh, acc[st][tt], 0, 0, 0);
                }
            }
        }

        if (s < 23) STAGE_WRITE(cur ^ 1); // vmcnt wait lands here, after MFMAs
        lgkm_barrier();
    }

    // C/D layout: col = lane&15, row = (lane>>4)*4 + reg  [m89-verified]
    #pragma unroll
    for (int tt = 0; tt < 7; ++tt) {
        const int nt = wc + 4 * tt;
        if (nt < 25) {
            const int n = nt * 16 + fr;
            #pragma unroll
            for (int st = 0; st < 4; ++st) {
                #pragma unroll
                for (int r = 0; r < 4; ++r) {
                    const int m = m0 + rb + st * 16 + (lane >> 4) * 4 + r;
                    xp[(size_t)m * G4 + n] = acc[st][tt][r] + bias_t[tt];
                }
            }
        }
    }
    #undef STAGE_LOAD
    #undef STAGE_WRITE
}

// ---------------------------------------------------------------------------
// Kernel 2: LSTM scan. 448 threads (7 FULL waves), tid = 4*j + g.
//   Each lane owns one CONTIGUOUS 100-float W_hh gate-row (25 float4 loads —
//   the round-2 shape the allocator provably keeps resident). 50 pk_fma/step,
//   activated gate exchanged via quad_perm DPP, one fenced lgkm-only barrier
//   per step, xp prefetched 2 steps ahead. j>99 lanes compute on a clamped
//   row and never write.
// ---------------------------------------------------------------------------
__global__ __launch_bounds__(448, 1) void lstm_scan(
    const float* __restrict__ xp,    // (T*B, 400)
    const float* __restrict__ Whh,   // (400, 100)
    float* __restrict__ hs)          // (T*B, 100)
{
    const int b   = blockIdx.x;
    const int tid = threadIdx.x;
    const int g   = tid & 3;         // gate 0=i 1=f 2=g 3=o
    const int j   = tid >> 2;        // hidden unit 0..111
    const int jc  = (j < H_DIM) ? j : (H_DIM - 1);
    const int row = g * H_DIM + jc;  // W_hh / xp gate-row

    __shared__ __align__(16) float hbuf[2][H_DIM];

    // one contiguous 100-float row -> exactly 25 float4 loads
    f32x2 w2[50];
    {
        const float* wrow = Whh + (size_t)row * H_DIM;
        #pragma unroll
        for (int i = 0; i < 25; ++i) {
            float4 v = *reinterpret_cast<const float4*>(&wrow[4 * i]);
            w2[2 * i]     = (f32x2){v.x, v.y};
            w2[2 * i + 1] = (f32x2){v.z, v.w};
        }
    }

    if (tid < H_DIM) { hbuf[0][tid] = 0.f; hbuf[1][tid] = 0.f; }

    const bool writer = (g == 0) && (j < H_DIM);

    // unified activation: act = s*sigm(s*x) - (s-1); s=2 for tanh gate (g==2)
    const float s_act = (g == 2) ? 2.0f : 1.0f;
    const float nsl2  = -s_act * 1.44269504088896f;
    const float nsm1  = 1.0f - s_act;

    float c = 0.f;
    const float* xp_ptr = xp + (size_t)b * G4 + row;
    float*       hs_ptr = hs + (size_t)b * H_DIM + jc;
    const size_t xstride = (size_t)B_DIM * G4;

    float xpv   = xp_ptr[0];
    float xp_n1 = xp_ptr[xstride];
    __syncthreads();

    int p = 0;
    for (int t = 0; t < T_DIM; ++t) {
        float xp_n2 = 0.f;
        if (t + 2 < T_DIM) xp_n2 = xp_ptr[2 * xstride];   // uniform branch
        xp_ptr += xstride;

        // full 100-MAC dot for this gate-row: 25 broadcast ds_read_b128,
        // 50 pk_fma into 2 packed accumulators
        f32x2 a0 = {xpv, 0.f};
        f32x2 a1 = {0.f, 0.f};
        const float* hb = hbuf[p];
        #pragma unroll
        for (int k = 0; k < 25; ++k) {
            float4 hv = *reinterpret_cast<const float4*>(&hb[4 * k]);
            a0 = __builtin_elementwise_fma(w2[2 * k],     (f32x2){hv.x, hv.y}, a0);
            a1 = __builtin_elementwise_fma(w2[2 * k + 1], (f32x2){hv.z, hv.w}, a1);
        }
        const float pre = (a0.x + a0.y) + (a1.x + a1.y);

        // lane activates only its own gate
        const float act = fmaf(s_act,
            fast_rcp(1.0f + __builtin_amdgcn_exp2f(nsl2 * pre)), nsm1);

        // quad broadcast of activated gates: slot 0=i, 1=f, 2=g, 3=o
        const float i_ = qperm<0x00>(act);
        const float f_ = qperm<0x55>(act);
        const float g_ = qperm<0xAA>(act);
        const float o_ = qperm<0xFF>(act);

        c = fmaf(f_, c, i_ * g_);
        const float h = o_ * tanh_f(c);

        if (writer) {
            hbuf[p ^ 1][jc] = h;
            *hs_ptr = h;
        }
        hs_ptr += B_DIM * H_DIM;
        lgkm_barrier();
        p ^= 1;
        xpv   = xp_n1;
        xp_n1 = xp_n2;
    }
}

// ---------------------------------------------------------------------------
// Kernel 3: FC. out[t,o] = fc_b[o] + hs[t,:] . fcW[o,:]
// ---------------------------------------------------------------------------
__global__ __launch_bounds__(256) void fc_kernel(
    const float* __restrict__ hs,    // (T, 5000)
    const float* __restrict__ fcW,   // (2, 5000)
    const float* __restrict__ fcb,
    float* __restrict__ out)         // (T, 2)
{
    const int t   = blockIdx.x;
    const int tid = threadIdx.x;

    float p0 = 0.f, p1 = 0.f;
    for (int k = tid * 4; k < 5000; k += 1024) {
        const float4 hv = *reinterpret_cast<const float4*>(&hs[(size_t)t * 5000 + k]);
        const float4 w0 = *reinterpret_cast<const float4*>(&fcW[k]);
        const float4 w1 = *reinterpret_cast<const float4*>(&fcW[5000 + k]);
        p0 += hv.x * w0.x + hv.y * w0.y + hv.z * w0.z + hv.w * w0.w;
        p1 += hv.x * w1.x + hv.y * w1.y + hv.z * w1.z + hv.w * w1.w;
    }
    #pragma unroll
    for (int off = 32; off > 0; off >>= 1) {
        p0 += __shfl_xor(p0, off);
        p1 += __shfl_xor(p1, off);
    }
    __shared__ float red[8];
    const int wv = tid >> 6;
    if ((tid & 63) == 0) { red[wv * 2] = p0; red[wv * 2 + 1] = p1; }
    __syncthreads();
    if (tid == 0) {
        out[2 * t]     = fcb[0] + red[0] + red[2] + red[4] + red[6];
        out[2 * t + 1] = fcb[1] + red[1] + red[3] + red[5] + red[7];
    }
}

// ---------------------------------------------------------------------------
extern "C" void kernel_launch(void* const* d_in, const int* in_sizes, int n_in,
                              void* d_out, int out_size, void* d_ws, size_t ws_size,
                              hipStream_t stream) {
    const float* x   = (const float*)d_in[0];
    const float* Wih = (const float*)d_in[1];
    const float* Whh = (const float*)d_in[2];
    const float* bih = (const float*)d_in[3];
    const float* bhh = (const float*)d_in[4];
    const float* fcW = (const float*)d_in[5];
    const float* fcb = (const float*)d_in[6];
    float* out = (float*)d_out;

    // ws layout: xp (163.84 MB) | Whi (614.4 KB) | Wlo (614.4 KB) | hs (40.96 MB)
    char* ws = (char*)d_ws;
    float*          xp  = (float*)ws;
    unsigned short* Whi = (unsigned short*)(ws + (size_t)M_DIM * G4 * 4);
    unsigned short* Wlo = Whi + (size_t)G4 * KPAD;
    float*          hs  = (float*)((char*)(Wlo + (size_t)G4 * KPAD));

    wconv<<<(G4 * KPAD + 255) / 256, 256, 0, stream>>>(Wih, Whi, Wlo);

    xproj_mfma<<<M_DIM / 128, 512, 0, stream>>>(x, Whi, Wlo, bih, bhh, xp);

    lstm_scan<<<B_DIM, 448, 0, stream>>>(xp, Whh, hs);

    fc_kernel<<<T_DIM, 256, 0, stream>>>(hs, fcW, fcb, out);
}

// Round 8
// 1615.295 us; speedup vs baseline: 1.0303x; 1.0192x over previous
//
#include <hip/hip_runtime.h>

#define T_DIM 2048
#define B_DIM 50
#define F_DIM 750
#define H_DIM 100
#define G4    400             // 4*H
#define M_DIM (T_DIM * B_DIM) // 102400
#define KPAD  768             // F padded to MFMA-friendly K

typedef __attribute__((ext_vector_type(8))) short short8v;  // 8 bf16
typedef __attribute__((ext_vector_type(4))) float f32x4;
typedef __attribute__((ext_vector_type(2))) float f32x2;

__device__ __forceinline__ float fast_rcp(float x) { return __builtin_amdgcn_rcpf(x); }
__device__ __forceinline__ float tanh_f(float x) {
    return 1.0f - 2.0f * fast_rcp(__expf(2.0f * x) + 1.0f);
}

__device__ __forceinline__ unsigned short f2bf_rne(float f) {
    unsigned int u = __float_as_uint(f);
    u = (u + 0x7FFFu + ((u >> 16) & 1u)) >> 16;
    return (unsigned short)u;
}
__device__ __forceinline__ float bf2f(unsigned short h) {
    return __uint_as_float(((unsigned int)h) << 16);
}

template <int CTRL>
__device__ __forceinline__ float qperm(float x) {
    return __int_as_float(__builtin_amdgcn_mov_dpp(__float_as_int(x), CTRL, 0xF, 0xF, false));
}

// lgkm-only barrier, fenced against scheduler motion (rule #18 hygiene)
__device__ __forceinline__ void lgkm_barrier() {
    __builtin_amdgcn_sched_barrier(0);
    asm volatile("s_waitcnt lgkmcnt(0)\ns_barrier" ::: "memory");
    __builtin_amdgcn_sched_barrier(0);
}

// ---------------------------------------------------------------------------
// Kernel 0a: W_ih (400x750 fp32) -> W_hi/W_lo (400x768 bf16, k-padded 0). RNE.
// ---------------------------------------------------------------------------
__global__ __launch_bounds__(256) void wconv(
    const float* __restrict__ W,
    unsigned short* __restrict__ Whi,
    unsigned short* __restrict__ Wlo)
{
    int i = blockIdx.x * 256 + threadIdx.x;
    if (i >= G4 * KPAD) return;
    int g = i / KPAD, k = i - g * KPAD;
    float v = (k < F_DIM) ? W[g * F_DIM + k] : 0.f;
    unsigned short h = f2bf_rne(v);
    Whi[i] = h;
    Wlo[i] = f2bf_rne(v - bf2f(h));
}

// ---------------------------------------------------------------------------
// Kernel 0b: repack W_hh for the quarter-split scan.
//   Lane (j,q) gets 112 contiguous floats: gate g in [g*28, g*28+28),
//   entry r = Whh[(g*100+j)*100 + 25q + r] for r<25, 0 for pads.
// ---------------------------------------------------------------------------
__global__ __launch_bounds__(256) void whh_pack(
    const float* __restrict__ Whh,   // (400, 100)
    float* __restrict__ wpack)       // (400 lanes, 112)
{
    int i = blockIdx.x * 256 + threadIdx.x;
    if (i >= 400 * 112) return;
    int lane = i / 112, rem = i - lane * 112;
    int g = rem / 28, r = rem - g * 28;
    int j = lane >> 2, q = lane & 3;
    wpack[i] = (r < 25) ? Whh[(size_t)(g * H_DIM + j) * H_DIM + 25 * q + r] : 0.f;
}

// ---------------------------------------------------------------------------
// Kernel 1: xp = x @ W_ih^T + b via bf16 split MFMA.  M-tile 128, 8 waves.
//   (unchanged from round 7)
// ---------------------------------------------------------------------------
__global__ __launch_bounds__(512, 1) void xproj_mfma(
    const float* __restrict__ x,            // (M, 750)
    const unsigned short* __restrict__ Whi, // (400, 768) bf16
    const unsigned short* __restrict__ Wlo,
    const float* __restrict__ bih,
    const float* __restrict__ bhh,
    float* __restrict__ xp)                 // (M, 400)
{
    const int m0   = blockIdx.x * 128;
    const int tid  = threadIdx.x;
    const int lane = tid & 63;
    const int w    = tid >> 6;            // wave 0..7
    const int rb   = (w >> 2) * 64;       // row block 0 / 64
    const int wc   = w & 3;               // col wave 0..3
    const int fr   = lane & 15;
    const int fk   = (lane >> 4) * 8;

    __shared__ unsigned short Ahi[2][128][40];   // 20 KB
    __shared__ unsigned short Alo[2][128][40];   // 20 KB

    f32x4 acc[4][7];
    #pragma unroll
    for (int s = 0; s < 4; ++s)
        #pragma unroll
        for (int t = 0; t < 7; ++t)
            acc[s][t] = (f32x4){0.f, 0.f, 0.f, 0.f};

    float bias_t[7];
    #pragma unroll
    for (int tt = 0; tt < 7; ++tt) {
        const int nt = wc + 4 * tt;
        if (nt < 25) {
            const int n = nt * 16 + fr;
            bias_t[tt] = bih[n] + bhh[n];
        } else bias_t[tt] = 0.f;
    }

    const int sr = tid >> 2;          // row 0..127
    const int sc = (tid & 3) * 8;     // k-chunk 0/8/16/24
    const float* xrow = x + (size_t)(m0 + sr) * F_DIM;

    float f[8];

    #define STAGE_LOAD(KS)                                                     \
    {                                                                          \
        const int kg = (KS) * 32 + sc;                                         \
        _Pragma("unroll")                                                      \
        for (int i = 0; i < 8; i += 2) {                                       \
            if (kg + i + 1 < F_DIM) {                                          \
                float2 v = *reinterpret_cast<const float2*>(&xrow[kg + i]);    \
                f[i] = v.x; f[i + 1] = v.y;                                    \
            } else {                                                           \
                f[i]     = (kg + i < F_DIM) ? xrow[kg + i] : 0.f;              \
                f[i + 1] = 0.f;                                                \
            }                                                                  \
        }                                                                      \
    }

    #define STAGE_WRITE(NB)                                                    \
    {                                                                          \
        short8v vh, vl;                                                        \
        _Pragma("unroll")                                                      \
        for (int i = 0; i < 8; ++i) {                                          \
            unsigned int u = __float_as_uint(f[i]);                            \
            vh[i] = (short)(u >> 16);                                          \
            float r = f[i] - __uint_as_float(u & 0xffff0000u);                 \
            vl[i] = (short)(__float_as_uint(r) >> 16);                         \
        }                                                                      \
        *reinterpret_cast<short8v*>(&Ahi[NB][sr][sc]) = vh;                    \
        *reinterpret_cast<short8v*>(&Alo[NB][sr][sc]) = vl;                    \
    }

    STAGE_LOAD(0);
    STAGE_WRITE(0);
    lgkm_barrier();

    for (int s = 0; s < 24; ++s) {
        const int cur = s & 1;
        short8v ah[4], al[4];
        #pragma unroll
        for (int st = 0; st < 4; ++st) {
            ah[st] = *reinterpret_cast<const short8v*>(&Ahi[cur][rb + st * 16 + fr][fk]);
            al[st] = *reinterpret_cast<const short8v*>(&Alo[cur][rb + st * 16 + fr][fk]);
        }

        if (s < 23) STAGE_LOAD(s + 1);    // issue loads early; consume after MFMA

        const int kb = s * 32 + fk;
        #pragma unroll
        for (int tt = 0; tt < 7; ++tt) {
            const int nt = wc + 4 * tt;
            if (nt < 25) {
                const int n = nt * 16 + fr;
                const short8v bh = *reinterpret_cast<const short8v*>(&Whi[n * KPAD + kb]);
                const short8v bl = *reinterpret_cast<const short8v*>(&Wlo[n * KPAD + kb]);
                #pragma unroll
                for (int st = 0; st < 4; ++st) {
                    acc[st][tt] = __builtin_amdgcn_mfma_f32_16x16x32_bf16(ah[st], bh, acc[st][tt], 0, 0, 0);
                    acc[st][tt] = __builtin_amdgcn_mfma_f32_16x16x32_bf16(ah[st], bl, acc[st][tt], 0, 0, 0);
                    acc[st][tt] = __builtin_amdgcn_mfma_f32_16x16x32_bf16(al[st], bh, acc[st][tt], 0, 0, 0);
                }
            }
        }

        if (s < 23) STAGE_WRITE(cur ^ 1); // vmcnt wait lands here, after MFMAs
        lgkm_barrier();
    }

    // C/D layout: col = lane&15, row = (lane>>4)*4 + reg  [m89-verified]
    #pragma unroll
    for (int tt = 0; tt < 7; ++tt) {
        const int nt = wc + 4 * tt;
        if (nt < 25) {
            const int n = nt * 16 + fr;
            #pragma unroll
            for (int st = 0; st < 4; ++st) {
                #pragma unroll
                for (int r = 0; r < 4; ++r) {
                    const int m = m0 + rb + st * 16 + (lane >> 4) * 4 + r;
                    xp[(size_t)m * G4 + n] = acc[st][tt][r] + bias_t[tt];
                }
            }
        }
    }
    #undef STAGE_LOAD
    #undef STAGE_WRITE
}

// ---------------------------------------------------------------------------
// Kernel 2: LSTM scan, quarter-split quad cell with REGISTER-RESIDENT weights.
//   amdgpu_waves_per_eu(1,2): caps the scheduler's occupancy target at 2
//   waves/EU -> 256-VGPR budget (only 50 workgroups exist; high occupancy
//   could never materialize anyway). Lane (j,q): k-quarter [25q,25q+25) of
//   all 4 gates of unit j, weights = 112 contiguous floats from wpack
//   (28 float4 loads). 56 pk_fma/step, 7 ds_read_b128/lane/step, DPP quad
//   butterfly + lane-specialized activation, fenced lgkm-only barrier.
// ---------------------------------------------------------------------------
__global__ __attribute__((amdgpu_waves_per_eu(1, 2))) __launch_bounds__(448)
void lstm_scan(
    const float* __restrict__ xp,    // (T*B, 400)
    const float* __restrict__ wpack, // (400, 112) packed W_hh
    float* __restrict__ hs)          // (T*B, 100)
{
    const int b   = blockIdx.x;
    const int tid = threadIdx.x;
    const int q   = tid & 3;         // k-quarter
    const int j   = tid >> 2;        // hidden unit 0..111
    const int jc  = (j < H_DIM) ? j : (H_DIM - 1);
    const int row = q * H_DIM + jc;  // xp column for gate q of unit j

    __shared__ __align__(16) float hbuf[2][112];   // quarters at 28-float offsets

    // 112 contiguous weights for this lane: 28 float4 loads -> 56 f32x2
    f32x2 w2[56];
    {
        const float* wb = wpack + (size_t)((jc << 2) + q) * 112;
        #pragma unroll
        for (int i = 0; i < 28; ++i) {
            float4 v = *reinterpret_cast<const float4*>(&wb[4 * i]);
            w2[2 * i]     = (f32x2){v.x, v.y};
            w2[2 * i + 1] = (f32x2){v.z, v.w};
        }
    }

    if (tid < 112) { hbuf[0][tid] = 0.f; hbuf[1][tid] = 0.f; }

    const int hpos = (jc / 25) * 28 + (jc % 25);
    const bool writer = (q == 0) && (j < H_DIM);

    // unified activation: act = s*sigm(s*x) - (s-1); s=2 for tanh gate (q==2)
    const float s_act = (q == 2) ? 2.0f : 1.0f;
    const float nsl2  = -s_act * 1.44269504088896f;
    const float nsm1  = 1.0f - s_act;

    float c = 0.f;
    const float* xp_ptr = xp + (size_t)b * G4 + row;
    float*       hs_ptr = hs + (size_t)b * H_DIM + jc;
    const size_t xstride = (size_t)B_DIM * G4;

    float xpv   = xp_ptr[0];
    float xp_n1 = xp_ptr[xstride];
    __syncthreads();

    int p = 0;
    for (int t = 0; t < T_DIM; ++t) {
        float xp_n2 = 0.f;
        if (t + 2 < T_DIM) xp_n2 = xp_ptr[2 * xstride];   // uniform branch
        xp_ptr += xstride;

        // packed partial dots over this lane's 28-float (padded) quarter
        f32x2 a0 = {(q == 0) ? xpv : 0.f, 0.f};
        f32x2 a1 = {(q == 1) ? xpv : 0.f, 0.f};
        f32x2 a2 = {(q == 2) ? xpv : 0.f, 0.f};
        f32x2 a3 = {(q == 3) ? xpv : 0.f, 0.f};
        const float* hq = &hbuf[p][28 * q];
        #pragma unroll
        for (int k = 0; k < 7; ++k) {
            float4 hv = *reinterpret_cast<const float4*>(hq + 4 * k);
            f32x2 hlo = {hv.x, hv.y};
            f32x2 hhi = {hv.z, hv.w};
            a0 = __builtin_elementwise_fma(w2[2 * k],          hlo, a0);
            a0 = __builtin_elementwise_fma(w2[2 * k + 1],      hhi, a0);
            a1 = __builtin_elementwise_fma(w2[14 + 2 * k],     hlo, a1);
            a1 = __builtin_elementwise_fma(w2[14 + 2 * k + 1], hhi, a1);
            a2 = __builtin_elementwise_fma(w2[28 + 2 * k],     hlo, a2);
            a2 = __builtin_elementwise_fma(w2[28 + 2 * k + 1], hhi, a2);
            a3 = __builtin_elementwise_fma(w2[42 + 2 * k],     hlo, a3);
            a3 = __builtin_elementwise_fma(w2[42 + 2 * k + 1], hhi, a3);
        }
        float ac0 = a0.x + a0.y;
        float ac1 = a1.x + a1.y;
        float ac2 = a2.x + a2.y;
        float ac3 = a3.x + a3.y;

        // quad butterfly (VALU DPP): full sums in all lanes
        ac0 += qperm<0xB1>(ac0);
        ac1 += qperm<0xB1>(ac1);
        ac2 += qperm<0xB1>(ac2);
        ac3 += qperm<0xB1>(ac3);
        ac0 += qperm<0x4E>(ac0);
        ac1 += qperm<0x4E>(ac1);
        ac2 += qperm<0x4E>(ac2);
        ac3 += qperm<0x4E>(ac3);

        // lane activates only its own gate
        float pre = ac0;
        pre = (q == 1) ? ac1 : pre;
        pre = (q == 2) ? ac2 : pre;
        pre = (q == 3) ? ac3 : pre;
        const float act = fmaf(s_act,
            fast_rcp(1.0f + __builtin_amdgcn_exp2f(nsl2 * pre)), nsm1);

        // quad broadcast of activated gates: slot 0=i, 1=f, 2=g, 3=o
        const float i_ = qperm<0x00>(act);
        const float f_ = qperm<0x55>(act);
        const float g_ = qperm<0xAA>(act);
        const float o_ = qperm<0xFF>(act);

        c = fmaf(f_, c, i_ * g_);
        const float h = o_ * tanh_f(c);

        if (writer) {
            hbuf[p ^ 1][hpos] = h;
            *hs_ptr = h;
        }
        hs_ptr += B_DIM * H_DIM;
        lgkm_barrier();
        p ^= 1;
        xpv   = xp_n1;
        xp_n1 = xp_n2;
    }
}

// ---------------------------------------------------------------------------
// Kernel 3: FC. out[t,o] = fc_b[o] + hs[t,:] . fcW[o,:]
// ---------------------------------------------------------------------------
__global__ __launch_bounds__(256) void fc_kernel(
    const float* __restrict__ hs,    // (T, 5000)
    const float* __restrict__ fcW,   // (2, 5000)
    const float* __restrict__ fcb,
    float* __restrict__ out)         // (T, 2)
{
    const int t   = blockIdx.x;
    const int tid = threadIdx.x;

    float p0 = 0.f, p1 = 0.f;
    for (int k = tid * 4; k < 5000; k += 1024) {
        const float4 hv = *reinterpret_cast<const float4*>(&hs[(size_t)t * 5000 + k]);
        const float4 w0 = *reinterpret_cast<const float4*>(&fcW[k]);
        const float4 w1 = *reinterpret_cast<const float4*>(&fcW[5000 + k]);
        p0 += hv.x * w0.x + hv.y * w0.y + hv.z * w0.z + hv.w * w0.w;
        p1 += hv.x * w1.x + hv.y * w1.y + hv.z * w1.z + hv.w * w1.w;
    }
    #pragma unroll
    for (int off = 32; off > 0; off >>= 1) {
        p0 += __shfl_xor(p0, off);
        p1 += __shfl_xor(p1, off);
    }
    __shared__ float red[8];
    const int wv = tid >> 6;
    if ((tid & 63) == 0) { red[wv * 2] = p0; red[wv * 2 + 1] = p1; }
    __syncthreads();
    if (tid == 0) {
        out[2 * t]     = fcb[0] + red[0] + red[2] + red[4] + red[6];
        out[2 * t + 1] = fcb[1] + red[1] + red[3] + red[5] + red[7];
    }
}

// ---------------------------------------------------------------------------
extern "C" void kernel_launch(void* const* d_in, const int* in_sizes, int n_in,
                              void* d_out, int out_size, void* d_ws, size_t ws_size,
                              hipStream_t stream) {
    const float* x   = (const float*)d_in[0];
    const float* Wih = (const float*)d_in[1];
    const float* Whh = (const float*)d_in[2];
    const float* bih = (const float*)d_in[3];
    const float* bhh = (const float*)d_in[4];
    const float* fcW = (const float*)d_in[5];
    const float* fcb = (const float*)d_in[6];
    float* out = (float*)d_out;

    // ws layout: xp (163.84 MB) | Whi | Wlo (0.6 MB each) | hs (40.96 MB) | wpack (179 KB)
    char* ws = (char*)d_ws;
    float*          xp    = (float*)ws;
    unsigned short* Whi   = (unsigned short*)(ws + (size_t)M_DIM * G4 * 4);
    unsigned short* Wlo   = Whi + (size_t)G4 * KPAD;
    float*          hs    = (float*)((char*)(Wlo + (size_t)G4 * KPAD));
    float*          wpack = hs + (size_t)M_DIM * H_DIM;

    wconv<<<(G4 * KPAD + 255) / 256, 256, 0, stream>>>(Wih, Whi, Wlo);
    whh_pack<<<(400 * 112 + 255) / 256, 256, 0, stream>>>(Whh, wpack);

    xproj_mfma<<<M_DIM / 128, 512, 0, stream>>>(x, Whi, Wlo, bih, bhh, xp);

    lstm_scan<<<B_DIM, 448, 0, stream>>>(xp, wpack, hs);

    fc_kernel<<<T_DIM, 256, 0, stream>>>(hs, fcW, fcb, out);
}

// Round 9
// 1604.977 us; speedup vs baseline: 1.0370x; 1.0064x over previous
//
#include <hip/hip_runtime.h>

#define T_DIM 2048
#define B_DIM 50
#define F_DIM 750
#define H_DIM 100
#define G4    400             // 4*H
#define M_DIM (T_DIM * B_DIM) // 102400
#define KPAD  768             // F padded to MFMA-friendly K

typedef __attribute__((ext_vector_type(8))) short short8v;  // 8 bf16
typedef __attribute__((ext_vector_type(4))) float f32x4;
typedef __attribute__((ext_vector_type(2))) float f32x2;

__device__ __forceinline__ float fast_rcp(float x) { return __builtin_amdgcn_rcpf(x); }
__device__ __forceinline__ float tanh_f(float x) {
    return 1.0f - 2.0f * fast_rcp(__expf(2.0f * x) + 1.0f);
}

__device__ __forceinline__ unsigned short f2bf_rne(float f) {
    unsigned int u = __float_as_uint(f);
    u = (u + 0x7FFFu + ((u >> 16) & 1u)) >> 16;
    return (unsigned short)u;
}
__device__ __forceinline__ float bf2f(unsigned short h) {
    return __uint_as_float(((unsigned int)h) << 16);
}

template <int CTRL>
__device__ __forceinline__ float qperm(float x) {
    return __int_as_float(__builtin_amdgcn_mov_dpp(__float_as_int(x), CTRL, 0xF, 0xF, false));
}

// lgkm-only barrier, fenced against scheduler motion (rule #18 hygiene)
__device__ __forceinline__ void lgkm_barrier() {
    __builtin_amdgcn_sched_barrier(0);
    asm volatile("s_waitcnt lgkmcnt(0)\ns_barrier" ::: "memory");
    __builtin_amdgcn_sched_barrier(0);
}

// ---------------------------------------------------------------------------
// Kernel 0a: W_ih (400x750 fp32) -> W_hi/W_lo (400x768 bf16, k-padded 0). RNE.
// ---------------------------------------------------------------------------
__global__ __launch_bounds__(256) void wconv(
    const float* __restrict__ W,
    unsigned short* __restrict__ Whi,
    unsigned short* __restrict__ Wlo)
{
    int i = blockIdx.x * 256 + threadIdx.x;
    if (i >= G4 * KPAD) return;
    int g = i / KPAD, k = i - g * KPAD;
    float v = (k < F_DIM) ? W[g * F_DIM + k] : 0.f;
    unsigned short h = f2bf_rne(v);
    Whi[i] = h;
    Wlo[i] = f2bf_rne(v - bf2f(h));
}

// ---------------------------------------------------------------------------
// Kernel 0b: repack W_hh for the quarter-split scan.
//   Lane (j,q) gets 112 contiguous floats: gate g in [g*28, g*28+28),
//   entry r = Whh[(g*100+j)*100 + 25q + r] for r<25, 0 for pads.
// ---------------------------------------------------------------------------
__global__ __launch_bounds__(256) void whh_pack(
    const float* __restrict__ Whh,   // (400, 100)
    float* __restrict__ wpack)       // (400 lanes, 112)
{
    int i = blockIdx.x * 256 + threadIdx.x;
    if (i >= 400 * 112) return;
    int lane = i / 112, rem = i - lane * 112;
    int g = rem / 28, r = rem - g * 28;
    int j = lane >> 2, q = lane & 3;
    wpack[i] = (r < 25) ? Whh[(size_t)(g * H_DIM + j) * H_DIM + 25 * q + r] : 0.f;
}

// ---------------------------------------------------------------------------
// Kernel 1: xp = x @ W_ih^T + b via bf16 split MFMA.  M-tile 128, 8 waves.
//   (unchanged from round 8)
// ---------------------------------------------------------------------------
__global__ __launch_bounds__(512, 1) void xproj_mfma(
    const float* __restrict__ x,            // (M, 750)
    const unsigned short* __restrict__ Whi, // (400, 768) bf16
    const unsigned short* __restrict__ Wlo,
    const float* __restrict__ bih,
    const float* __restrict__ bhh,
    float* __restrict__ xp)                 // (M, 400)
{
    const int m0   = blockIdx.x * 128;
    const int tid  = threadIdx.x;
    const int lane = tid & 63;
    const int w    = tid >> 6;            // wave 0..7
    const int rb   = (w >> 2) * 64;       // row block 0 / 64
    const int wc   = w & 3;               // col wave 0..3
    const int fr   = lane & 15;
    const int fk   = (lane >> 4) * 8;

    __shared__ unsigned short Ahi[2][128][40];   // 20 KB
    __shared__ unsigned short Alo[2][128][40];   // 20 KB

    f32x4 acc[4][7];
    #pragma unroll
    for (int s = 0; s < 4; ++s)
        #pragma unroll
        for (int t = 0; t < 7; ++t)
            acc[s][t] = (f32x4){0.f, 0.f, 0.f, 0.f};

    float bias_t[7];
    #pragma unroll
    for (int tt = 0; tt < 7; ++tt) {
        const int nt = wc + 4 * tt;
        if (nt < 25) {
            const int n = nt * 16 + fr;
            bias_t[tt] = bih[n] + bhh[n];
        } else bias_t[tt] = 0.f;
    }

    const int sr = tid >> 2;          // row 0..127
    const int sc = (tid & 3) * 8;     // k-chunk 0/8/16/24
    const float* xrow = x + (size_t)(m0 + sr) * F_DIM;

    float f[8];

    #define STAGE_LOAD(KS)                                                     \
    {                                                                          \
        const int kg = (KS) * 32 + sc;                                         \
        _Pragma("unroll")                                                      \
        for (int i = 0; i < 8; i += 2) {                                       \
            if (kg + i + 1 < F_DIM) {                                          \
                float2 v = *reinterpret_cast<const float2*>(&xrow[kg + i]);    \
                f[i] = v.x; f[i + 1] = v.y;                                    \
            } else {                                                           \
                f[i]     = (kg + i < F_DIM) ? xrow[kg + i] : 0.f;              \
                f[i + 1] = 0.f;                                                \
            }                                                                  \
        }                                                                      \
    }

    #define STAGE_WRITE(NB)                                                    \
    {                                                                          \
        short8v vh, vl;                                                        \
        _Pragma("unroll")                                                      \
        for (int i = 0; i < 8; ++i) {                                          \
            unsigned int u = __float_as_uint(f[i]);                            \
            vh[i] = (short)(u >> 16);                                          \
            float r = f[i] - __uint_as_float(u & 0xffff0000u);                 \
            vl[i] = (short)(__float_as_uint(r) >> 16);                         \
        }                                                                      \
        *reinterpret_cast<short8v*>(&Ahi[NB][sr][sc]) = vh;                    \
        *reinterpret_cast<short8v*>(&Alo[NB][sr][sc]) = vl;                    \
    }

    STAGE_LOAD(0);
    STAGE_WRITE(0);
    lgkm_barrier();

    for (int s = 0; s < 24; ++s) {
        const int cur = s & 1;
        short8v ah[4], al[4];
        #pragma unroll
        for (int st = 0; st < 4; ++st) {
            ah[st] = *reinterpret_cast<const short8v*>(&Ahi[cur][rb + st * 16 + fr][fk]);
            al[st] = *reinterpret_cast<const short8v*>(&Alo[cur][rb + st * 16 + fr][fk]);
        }

        if (s < 23) STAGE_LOAD(s + 1);    // issue loads early; consume after MFMA

        const int kb = s * 32 + fk;
        #pragma unroll
        for (int tt = 0; tt < 7; ++tt) {
            const int nt = wc + 4 * tt;
            if (nt < 25) {
                const int n = nt * 16 + fr;
                const short8v bh = *reinterpret_cast<const short8v*>(&Whi[n * KPAD + kb]);
                const short8v bl = *reinterpret_cast<const short8v*>(&Wlo[n * KPAD + kb]);
                #pragma unroll
                for (int st = 0; st < 4; ++st) {
                    acc[st][tt] = __builtin_amdgcn_mfma_f32_16x16x32_bf16(ah[st], bh, acc[st][tt], 0, 0, 0);
                    acc[st][tt] = __builtin_amdgcn_mfma_f32_16x16x32_bf16(ah[st], bl, acc[st][tt], 0, 0, 0);
                    acc[st][tt] = __builtin_amdgcn_mfma_f32_16x16x32_bf16(al[st], bh, acc[st][tt], 0, 0, 0);
                }
            }
        }

        if (s < 23) STAGE_WRITE(cur ^ 1); // vmcnt wait lands here, after MFMAs
        lgkm_barrier();
    }

    // C/D layout: col = lane&15, row = (lane>>4)*4 + reg  [m89-verified]
    #pragma unroll
    for (int tt = 0; tt < 7; ++tt) {
        const int nt = wc + 4 * tt;
        if (nt < 25) {
            const int n = nt * 16 + fr;
            #pragma unroll
            for (int st = 0; st < 4; ++st) {
                #pragma unroll
                for (int r = 0; r < 4; ++r) {
                    const int m = m0 + rb + st * 16 + (lane >> 4) * 4 + r;
                    xp[(size_t)m * G4 + n] = acc[st][tt][r] + bias_t[tt];
                }
            }
        }
    }
    #undef STAGE_LOAD
    #undef STAGE_WRITE
}

// ---------------------------------------------------------------------------
// Kernel 2: LSTM scan, quarter-split quad cell.
//   OCCUPANCY BRAKE: 148 KB dummy LDS forces 1 workgroup/CU -> 2 waves/EU ->
//   the register allocator's budget rises from ~72 (7-wave target, the
//   r4-r8 pathology) to 256 VGPRs, letting the 112-float per-lane W_hh
//   block actually stay register-resident. Costs nothing: grid=50 blocks on
//   256 CUs was already 1 block/CU.
// ---------------------------------------------------------------------------
__global__ __launch_bounds__(448, 1) void lstm_scan(
    const float* __restrict__ xp,    // (T*B, 400)
    const float* __restrict__ wpack, // (400, 112) packed W_hh
    float* __restrict__ hs)          // (T*B, 100)
{
    const int b   = blockIdx.x;
    const int tid = threadIdx.x;
    const int q   = tid & 3;         // k-quarter
    const int j   = tid >> 2;        // hidden unit 0..111
    const int jc  = (j < H_DIM) ? j : (H_DIM - 1);
    const int row = q * H_DIM + jc;  // xp column for gate q of unit j

    __shared__ __align__(16) float hbuf[2][112];     // quarters at 28-float offsets
    __shared__ float lds_occupancy_brake[37000];     // 148 KB, see header comment

    // keep the brake alive: opaque (runtime blockIdx) never-true guard
    if (b >= B_DIM) {
        lds_occupancy_brake[tid] = (float)tid;
        hbuf[0][tid & 1] = lds_occupancy_brake[(tid * 7) & 1023];
    }

    // 112 contiguous weights for this lane: 28 float4 loads -> 56 f32x2
    f32x2 w2[56];
    {
        const float* wb = wpack + (size_t)((jc << 2) + q) * 112;
        #pragma unroll
        for (int i = 0; i < 28; ++i) {
            float4 v = *reinterpret_cast<const float4*>(&wb[4 * i]);
            w2[2 * i]     = (f32x2){v.x, v.y};
            w2[2 * i + 1] = (f32x2){v.z, v.w};
        }
    }

    if (tid < 112) { hbuf[0][tid] = 0.f; hbuf[1][tid] = 0.f; }

    const int hpos = (jc / 25) * 28 + (jc % 25);
    const bool writer = (q == 0) && (j < H_DIM);

    // unified activation: act = s*sigm(s*x) - (s-1); s=2 for tanh gate (q==2)
    const float s_act = (q == 2) ? 2.0f : 1.0f;
    const float nsl2  = -s_act * 1.44269504088896f;
    const float nsm1  = 1.0f - s_act;

    float c = 0.f;
    const float* xp_ptr = xp + (size_t)b * G4 + row;
    float*       hs_ptr = hs + (size_t)b * H_DIM + jc;
    const size_t xstride = (size_t)B_DIM * G4;

    float xpv   = xp_ptr[0];
    float xp_n1 = xp_ptr[xstride];
    __syncthreads();

    int p = 0;
    for (int t = 0; t < T_DIM; ++t) {
        float xp_n2 = 0.f;
        if (t + 2 < T_DIM) xp_n2 = xp_ptr[2 * xstride];   // uniform branch
        xp_ptr += xstride;

        // packed partial dots over this lane's 28-float (padded) quarter
        f32x2 a0 = {(q == 0) ? xpv : 0.f, 0.f};
        f32x2 a1 = {(q == 1) ? xpv : 0.f, 0.f};
        f32x2 a2 = {(q == 2) ? xpv : 0.f, 0.f};
        f32x2 a3 = {(q == 3) ? xpv : 0.f, 0.f};
        const float* hq = &hbuf[p][28 * q];
        #pragma unroll
        for (int k = 0; k < 7; ++k) {
            float4 hv = *reinterpret_cast<const float4*>(hq + 4 * k);
            f32x2 hlo = {hv.x, hv.y};
            f32x2 hhi = {hv.z, hv.w};
            a0 = __builtin_elementwise_fma(w2[2 * k],          hlo, a0);
            a0 = __builtin_elementwise_fma(w2[2 * k + 1],      hhi, a0);
            a1 = __builtin_elementwise_fma(w2[14 + 2 * k],     hlo, a1);
            a1 = __builtin_elementwise_fma(w2[14 + 2 * k + 1], hhi, a1);
            a2 = __builtin_elementwise_fma(w2[28 + 2 * k],     hlo, a2);
            a2 = __builtin_elementwise_fma(w2[28 + 2 * k + 1], hhi, a2);
            a3 = __builtin_elementwise_fma(w2[42 + 2 * k],     hlo, a3);
            a3 = __builtin_elementwise_fma(w2[42 + 2 * k + 1], hhi, a3);
        }
        float ac0 = a0.x + a0.y;
        float ac1 = a1.x + a1.y;
        float ac2 = a2.x + a2.y;
        float ac3 = a3.x + a3.y;

        // quad butterfly (VALU DPP): full sums in all lanes
        ac0 += qperm<0xB1>(ac0);
        ac1 += qperm<0xB1>(ac1);
        ac2 += qperm<0xB1>(ac2);
        ac3 += qperm<0xB1>(ac3);
        ac0 += qperm<0x4E>(ac0);
        ac1 += qperm<0x4E>(ac1);
        ac2 += qperm<0x4E>(ac2);
        ac3 += qperm<0x4E>(ac3);

        // lane activates only its own gate
        float pre = ac0;
        pre = (q == 1) ? ac1 : pre;
        pre = (q == 2) ? ac2 : pre;
        pre = (q == 3) ? ac3 : pre;
        const float act = fmaf(s_act,
            fast_rcp(1.0f + __builtin_amdgcn_exp2f(nsl2 * pre)), nsm1);

        // quad broadcast of activated gates: slot 0=i, 1=f, 2=g, 3=o
        const float i_ = qperm<0x00>(act);
        const float f_ = qperm<0x55>(act);
        const float g_ = qperm<0xAA>(act);
        const float o_ = qperm<0xFF>(act);

        c = fmaf(f_, c, i_ * g_);
        const float h = o_ * tanh_f(c);

        if (writer) {
            hbuf[p ^ 1][hpos] = h;
            *hs_ptr = h;
        }
        hs_ptr += B_DIM * H_DIM;
        lgkm_barrier();
        p ^= 1;
        xpv   = xp_n1;
        xp_n1 = xp_n2;
    }
}

// ---------------------------------------------------------------------------
// Kernel 3: FC. out[t,o] = fc_b[o] + hs[t,:] . fcW[o,:]
// ---------------------------------------------------------------------------
__global__ __launch_bounds__(256) void fc_kernel(
    const float* __restrict__ hs,    // (T, 5000)
    const float* __restrict__ fcW,   // (2, 5000)
    const float* __restrict__ fcb,
    float* __restrict__ out)         // (T, 2)
{
    const int t   = blockIdx.x;
    const int tid = threadIdx.x;

    float p0 = 0.f, p1 = 0.f;
    for (int k = tid * 4; k < 5000; k += 1024) {
        const float4 hv = *reinterpret_cast<const float4*>(&hs[(size_t)t * 5000 + k]);
        const float4 w0 = *reinterpret_cast<const float4*>(&fcW[k]);
        const float4 w1 = *reinterpret_cast<const float4*>(&fcW[5000 + k]);
        p0 += hv.x * w0.x + hv.y * w0.y + hv.z * w0.z + hv.w * w0.w;
        p1 += hv.x * w1.x + hv.y * w1.y + hv.z * w1.z + hv.w * w1.w;
    }
    #pragma unroll
    for (int off = 32; off > 0; off >>= 1) {
        p0 += __shfl_xor(p0, off);
        p1 += __shfl_xor(p1, off);
    }
    __shared__ float red[8];
    const int wv = tid >> 6;
    if ((tid & 63) == 0) { red[wv * 2] = p0; red[wv * 2 + 1] = p1; }
    __syncthreads();
    if (tid == 0) {
        out[2 * t]     = fcb[0] + red[0] + red[2] + red[4] + red[6];
        out[2 * t + 1] = fcb[1] + red[1] + red[3] + red[5] + red[7];
    }
}

// ---------------------------------------------------------------------------
extern "C" void kernel_launch(void* const* d_in, const int* in_sizes, int n_in,
                              void* d_out, int out_size, void* d_ws, size_t ws_size,
                              hipStream_t stream) {
    const float* x   = (const float*)d_in[0];
    const float* Wih = (const float*)d_in[1];
    const float* Whh = (const float*)d_in[2];
    const float* bih = (const float*)d_in[3];
    const float* bhh = (const float*)d_in[4];
    const float* fcW = (const float*)d_in[5];
    const float* fcb = (const float*)d_in[6];
    float* out = (float*)d_out;

    // ws layout: xp (163.84 MB) | Whi | Wlo (0.6 MB each) | hs (40.96 MB) | wpack (179 KB)
    char* ws = (char*)d_ws;
    float*          xp    = (float*)ws;
    unsigned short* Whi   = (unsigned short*)(ws + (size_t)M_DIM * G4 * 4);
    unsigned short* Wlo   = Whi + (size_t)G4 * KPAD;
    float*          hs    = (float*)((char*)(Wlo + (size_t)G4 * KPAD));
    float*          wpack = hs + (size_t)M_DIM * H_DIM;

    wconv<<<(G4 * KPAD + 255) / 256, 256, 0, stream>>>(Wih, Whi, Wlo);
    whh_pack<<<(400 * 112 + 255) / 256, 256, 0, stream>>>(Whh, wpack);

    xproj_mfma<<<M_DIM / 128, 512, 0, stream>>>(x, Whi, Wlo, bih, bhh, xp);

    lstm_scan<<<B_DIM, 448, 0, stream>>>(xp, wpack, hs);

    fc_kernel<<<T_DIM, 256, 0, stream>>>(hs, fcW, fcb, out);
}